// Round 2
// baseline (420.948 us; speedup 1.0000x reference)
//
#include <hip/hip_runtime.h>

// ROI adaptive average pooling — batch-staged version, R4.
// B=8, C=1024, HW=14, N=512, FS=14, SCALE=1/16.
//
// R4 post-mortem of R3: halving phase-2 LDS instructions + conflict-free
// gather stride was NEUTRAL (kernel ~148us both ways) -> phase-2 LDS was not
// the bottleneck. Remaining structural waste: 16,384 blocks re-staged the
// same 6.4 MB input 64x (411 MB of L2/L3 reads contending with the 411 MB
// HBM write stream) and recomputed geometry 32x per ROI.
//
// R4 inverts the loop: block = (batch, 32-channel group, ROI-slice of 4).
// 1024 blocks. Stage the 25 KB plane slice ONCE, then sweep the ~16 ROIs of
// this batch/slice, computing geometry per ROI (196 threads) and running the
// R3 gather loop (245 threads, paired ds_read2, stride-49 positions).
// Reads drop 411 MB -> ~26 MB; writes (411 MB, the floor at ~65us) keep the
// fabric to themselves. Per-ROI work is shape-independent -> the fm-match
// branch is block-uniform -> barriers legal.

#define FS_      14
#define PER_CH   196               // 14*14
#define C_       1024
#define CPB      32                // channels per block
#define QPC      49                // positions per thread-stride (196/4)
#define NSTAGE4  (CPB * PER_CH / 4)  // 1568 float4 to stage
#define ACT      245               // active compute threads = 5*49
#define NROI     512
#define NSLICE   4
#define CAND     (NROI / NSLICE)   // 128 ROI candidates per slice

#if defined(__has_builtin)
# if __has_builtin(__builtin_amdgcn_global_load_lds)
#  define USE_GLL 1
# endif
#endif

__global__ __launch_bounds__(256) void roi_pool_kernel(
    const float* __restrict__ tensor,
    const float* __restrict__ roi,
    float* __restrict__ out)
{
    __shared__ float s_plane[CPB * PER_CH + 4];   // 25,104 B (+4 zeroed pad)
    __shared__ alignas(16) int   s_o00[PER_CH], s_o10[PER_CH];  // byte offsets
    __shared__ alignas(16) float s_mw[PER_CH], s_mh[PER_CH], s_inv[PER_CH];
    __shared__ int s_fm[CAND];                    // batch idx of each candidate

    // Block mapping: bx = ((b * 32) + cg) * 4 + slice
    const unsigned bx    = blockIdx.x;
    const unsigned slice = bx & 3u;
    const unsigned cg    = (bx >> 2) & 31u;
    const unsigned b     = bx >> 7;               // 0..7
    const unsigned c0    = cg * CPB;

    const unsigned tid = threadIdx.x;

    // ---- Phase 0: candidate batch indices + zero pad.
    if (tid < CAND) {
        s_fm[tid] = (int)roi[(size_t)(slice + 4u * tid) * 5];
    } else if (tid < CAND + 4u) {
        s_plane[CPB * PER_CH + (tid - CAND)] = 0.0f;  // zeroed overread pad
    }

    // ---- Phase 1: stage the 32 contiguous input planes of batch b, ONCE.
    const float4* __restrict__ src4 =
        (const float4*)(tensor + ((size_t)b * C_ + c0) * PER_CH);
    float4* __restrict__ dst4 = (float4*)s_plane;
#pragma unroll
    for (unsigned k = 0; k < 7; ++k) {
        unsigned fi = k * 256u + tid;
        if (fi < NSTAGE4) {
#if defined(USE_GLL)
            __builtin_amdgcn_global_load_lds(
                (const __attribute__((address_space(1))) void*)(src4 + fi),
                (__attribute__((address_space(3))) void*)(dst4 + fi),
                16, 0, 0);
#else
            dst4[fi] = src4[fi];
#endif
        }
    }

    __syncthreads();

    const unsigned tc = tid / QPC;         // 0..5 (>=5 means inactive spare)
    const unsigned q  = tid - tc * QPC;

    // ---- Phase 2: sweep candidate ROIs of this slice; process matches.
    for (unsigned ci = 0; ci < CAND; ++ci) {
        if (s_fm[ci] != (int)b) continue;          // block-uniform branch
        const unsigned n = slice + 4u * ci;        // ROI index

        // -- Geometry for this ROI (196 positions).
        if (tid < PER_CH) {
            const float* r = roi + (size_t)n * 5;
            const int x1 = max((int)floorf(r[1] * 0.0625f), 0);
            const int y1 = max((int)floorf(r[2] * 0.0625f), 0);
            const int x2 = min((int)ceilf(r[3] * 0.0625f), FS_);
            const int y2 = min((int)ceilf(r[4] * 0.0625f), FS_);
            const unsigned Lh = (unsigned)(x2 - x1);   // 1..14 guaranteed
            const unsigned Lw = (unsigned)(y2 - y1);

            const unsigned p = tid;
            const unsigned i = p / 14u;
            const unsigned j = p - i * 14u;
            const unsigned h0 = (i * Lh) / 14u;
            const unsigned h1 = ((i + 1u) * Lh + 13u) / 14u;
            const unsigned w0 = (j * Lw) / 14u;
            const unsigned w1 = ((j + 1u) * Lw + 13u) / 14u;
            const int dh = (int)(h1 - h0) - 1;     // 0 or 1
            const int dw = (int)(w1 - w0) - 1;     // 0 or 1
            const int a00 = (x1 + (int)h0) * FS_ + (y1 + (int)w0);
            s_o00[p] = a00 * 4;
            s_o10[p] = (a00 + FS_ * dh) * 4;
            s_mw[p]  = (float)dw;
            s_mh[p]  = (float)dh;
            const int cnt = (dh + 1) * (dw + 1);   // 1, 2, or 4
            s_inv[p] = (cnt == 1) ? 1.0f : ((cnt == 2) ? 0.5f : 0.25f);
        }
        __syncthreads();

        // -- Gather + store (245 active threads), identical to R3 inner loop.
        if (tid < ACT) {
            int   O00[4], O10[4];
            float MW[4], MH[4], INV[4];
#pragma unroll
            for (int k = 0; k < 4; ++k) {
                const unsigned p = q + QPC * (unsigned)k;
                O00[k] = s_o00[p];
                O10[k] = s_o10[p];
                MW[k]  = s_mw[p];
                MH[k]  = s_mh[p];
                INV[k] = s_inv[p];
            }

            float* __restrict__ ob =
                out + ((size_t)n * C_ + c0) * PER_CH + q;

#pragma unroll
            for (unsigned it = 0; it < 7; ++it) {
                const unsigned cl = it * 5u + tc;  // local channel
                if (cl >= CPB) continue;           // trims last iteration
                const char* pb = (const char*)s_plane + cl * (PER_CH * 4);
                float* __restrict__ op = ob + cl * PER_CH;

#pragma unroll
                for (int k = 0; k < 4; ++k) {
                    const char* p0 = pb + O00[k];
                    const float v00 = *(const float*)(p0);
                    const float v01 = *(const float*)(p0 + 4);  // ds_read2_b32
                    const char* p1 = pb + O10[k];
                    const float v10 = *(const float*)(p1);
                    const float v11 = *(const float*)(p1 + 4);
                    const float s = fmaf(MW[k], v01, v00)
                                  + MH[k] * fmaf(MW[k], v11, v10);
                    op[k * QPC] = s * INV[k];      // lanes q=0..48 coalesced
                }
            }
        }
        __syncthreads();   // geometry tables reused next matched ROI
    }
}

extern "C" void kernel_launch(void* const* d_in, const int* in_sizes, int n_in,
                              void* d_out, int out_size, void* d_ws, size_t ws_size,
                              hipStream_t stream) {
    const float* tensor = (const float*)d_in[0];   // [8,1024,14,14] f32
    const float* roi    = (const float*)d_in[1];   // [512,5] f32
    float* out = (float*)d_out;                    // [512,1024,14,14] f32

    const int blocks = 8 * 32 * NSLICE;            // 1024
    roi_pool_kernel<<<blocks, 256, 0, stream>>>(tensor, roi, out);
}

// Round 4
// 419.621 us; speedup vs baseline: 1.0032x; 1.0032x over previous
//
#include <hip/hip_runtime.h>

// ROI adaptive average pooling — R6: non-temporal quad stores (fixed type).
// B=8, C=1024, HW=14, N=512, FS=14, SCALE=1/16.
//
// R6 = R5 with the compile fix: __builtin_nontemporal_store rejects HIP's
// float4 class; bit-cast through a clang ext_vector_type(4) alias instead.
//
// Theory under test (unchanged): R3 (LDS insts halved, conflict-free) and
// R4 (reads /16) were both NULL -> kernel (~148us) is not LDS/read/VALU
// bound. Invariant: 411 MB store stream at effective ~2.7 TB/s. Candidate
// mechanism: L2 write-allocate / dirty-line RMW on plain global stores
// (411 MB through 32 MB L2 = 100% miss; RMW -> ~822 MB effective HBM
// traffic ~= 130us ~= observed). nt stores bypass L2 allocation.

#define FS_      14
#define PER_CH   196               // 14*14
#define C_       1024
#define CPB      32                // channels per block
#define QPC      49                // quads per channel (196/4)
#define NSTAGE4  (CPB * PER_CH / 4)  // 1568 float4 to stage
#define ACT      245               // active compute threads = 5*49

typedef float vfloat4 __attribute__((ext_vector_type(4)));

#if defined(__has_builtin)
# if __has_builtin(__builtin_amdgcn_global_load_lds)
#  define USE_GLL 1
# endif
# if __has_builtin(__builtin_nontemporal_store)
#  define USE_NT 1
# endif
#endif

__global__ __launch_bounds__(256) void roi_pool_kernel(
    const float* __restrict__ tensor,
    const float* __restrict__ roi,
    float* __restrict__ out)
{
    __shared__ float s_plane[CPB * PER_CH + 4];   // 25,104 B (+4 zeroed pad)
    __shared__ alignas(16) int   s_o00[PER_CH], s_o10[PER_CH];  // byte offsets
    __shared__ alignas(16) float s_mw[PER_CH], s_mh[PER_CH], s_inv[PER_CH];

    const unsigned bx = blockIdx.x;
    const unsigned n  = bx >> 5;            // ROI index
    const unsigned c0 = (bx & 31u) * CPB;   // first channel of this block

    // ROI row [batch_idx, x1, y1, x2, y2] in 224-px coords (uniform -> scalar).
    const float* r = roi + n * 5;
    const int fm = (int)r[0];
    const int x1 = max((int)floorf(r[1] * 0.0625f), 0);
    const int y1 = max((int)floorf(r[2] * 0.0625f), 0);
    const int x2 = min((int)ceilf(r[3] * 0.0625f), FS_);
    const int y2 = min((int)ceilf(r[4] * 0.0625f), FS_);
    const unsigned Lh = (unsigned)(x2 - x1);   // 1..14 guaranteed
    const unsigned Lw = (unsigned)(y2 - y1);

    const unsigned tid = threadIdx.x;

    // ---- Phase 1a: geometry tables (196 positions), byte offsets into a plane.
    if (tid < PER_CH) {
        const unsigned p = tid;
        const unsigned i = p / 14u;
        const unsigned j = p - i * 14u;
        const unsigned h0 = (i * Lh) / 14u;
        const unsigned h1 = ((i + 1u) * Lh + 13u) / 14u;
        const unsigned w0 = (j * Lw) / 14u;
        const unsigned w1 = ((j + 1u) * Lw + 13u) / 14u;
        const int dh = (int)(h1 - h0) - 1;     // 0 or 1
        const int dw = (int)(w1 - w0) - 1;     // 0 or 1
        const int a00 = (x1 + (int)h0) * FS_ + (y1 + (int)w0);
        s_o00[p] = a00 * 4;
        s_o10[p] = (a00 + FS_ * dh) * 4;
        s_mw[p]  = (float)dw;
        s_mh[p]  = (float)dh;
        const int cnt = (dh + 1) * (dw + 1);   // 1, 2, or 4
        s_inv[p] = (cnt == 1) ? 1.0f : ((cnt == 2) ? 0.5f : 0.25f);
    } else if (tid < PER_CH + 4u) {
        // Zero the overread pad — MUST be deterministic (0 * pad must be 0).
        s_plane[CPB * PER_CH + (tid - PER_CH)] = 0.0f;
    }

    // ---- Phase 1b: stage the 32 contiguous input planes (coalesced float4).
    const float4* __restrict__ src4 =
        (const float4*)(tensor + ((size_t)fm * C_ + c0) * PER_CH);
    float4* __restrict__ dst4 = (float4*)s_plane;
#pragma unroll
    for (unsigned k = 0; k < 7; ++k) {
        unsigned fi = k * 256u + tid;
        if (fi < NSTAGE4) {
#if defined(USE_GLL)
            __builtin_amdgcn_global_load_lds(
                (const __attribute__((address_space(1))) void*)(src4 + fi),
                (__attribute__((address_space(3))) void*)(dst4 + fi),
                16, 0, 0);
#else
            dst4[fi] = src4[fi];
#endif
        }
    }

    __syncthreads();

    // ---- Phase 2: thread owns contiguous quad positions 4q..4q+3 of every
    // 5th channel; 4 results pack into one non-temporal dwordx4 store.
    if (tid < ACT) {
        const unsigned tc = tid / QPC;         // 0..4
        const unsigned q  = tid - tc * QPC;    // fixed across iterations

        const int4   O00 = ((const int4*)s_o00)[q];
        const int4   O10 = ((const int4*)s_o10)[q];
        const float4 MW  = ((const float4*)s_mw)[q];
        const float4 MH  = ((const float4*)s_mh)[q];
        const float4 INV = ((const float4*)s_inv)[q];

        vfloat4* __restrict__ out4 =
            (vfloat4*)(out + ((size_t)n * C_ + c0) * PER_CH);

#pragma unroll
        for (unsigned it = 0; it < 7; ++it) {
            const unsigned cl = it * 5u + tc;  // local channel
            if (cl >= CPB) continue;           // only trims the last iteration
            const char* pb = (const char*)s_plane + cl * (PER_CH * 4);

            vfloat4 o;
            {
                const char* p0 = pb + O00.x;
                const char* p1 = pb + O10.x;
                const float v00 = *(const float*)(p0);
                const float v01 = *(const float*)(p0 + 4);  // ds_read2_b32
                const float v10 = *(const float*)(p1);
                const float v11 = *(const float*)(p1 + 4);
                o.x = (fmaf(MW.x, v01, v00) + MH.x * fmaf(MW.x, v11, v10)) * INV.x;
            }
            {
                const char* p0 = pb + O00.y;
                const char* p1 = pb + O10.y;
                const float v00 = *(const float*)(p0);
                const float v01 = *(const float*)(p0 + 4);
                const float v10 = *(const float*)(p1);
                const float v11 = *(const float*)(p1 + 4);
                o.y = (fmaf(MW.y, v01, v00) + MH.y * fmaf(MW.y, v11, v10)) * INV.y;
            }
            {
                const char* p0 = pb + O00.z;
                const char* p1 = pb + O10.z;
                const float v00 = *(const float*)(p0);
                const float v01 = *(const float*)(p0 + 4);
                const float v10 = *(const float*)(p1);
                const float v11 = *(const float*)(p1 + 4);
                o.z = (fmaf(MW.z, v01, v00) + MH.z * fmaf(MW.z, v11, v10)) * INV.z;
            }
            {
                const char* p0 = pb + O00.w;
                const char* p1 = pb + O10.w;
                const float v00 = *(const float*)(p0);
                const float v01 = *(const float*)(p0 + 4);
                const float v10 = *(const float*)(p1);
                const float v11 = *(const float*)(p1 + 4);
                o.w = (fmaf(MW.w, v01, v00) + MH.w * fmaf(MW.w, v11, v10)) * INV.w;
            }

            // qq = it*245 + tid -> coalesced; nt bypasses L2 allocation.
#if defined(USE_NT)
            __builtin_nontemporal_store(o, &out4[it * ACT + tid]);
#else
            out4[it * ACT + tid] = o;
#endif
        }
    }
}

extern "C" void kernel_launch(void* const* d_in, const int* in_sizes, int n_in,
                              void* d_out, int out_size, void* d_ws, size_t ws_size,
                              hipStream_t stream) {
    const float* tensor = (const float*)d_in[0];   // [8,1024,14,14] f32
    const float* roi    = (const float*)d_in[1];   // [512,5] f32
    float* out = (float*)d_out;                    // [512,1024,14,14] f32

    const int blocks = (out_size / (CPB * PER_CH));  // 512 * 32 = 16,384
    roi_pool_kernel<<<blocks, 256, 0, stream>>>(tensor, roi, out);
}